// Round 1
// baseline (971.288 us; speedup 1.0000x reference)
//
#include <hip/hip_runtime.h>

// Loss_Synonymy: per-row L2 distance -> tanh -> conditional relu -> global sum.
// B = 1048576 rows, D = 128 fp32. Memory-bound: ~1.08 GB read once.
// Layout: 32 lanes (half-wave) per row, float4 per lane = 512 B/row coalesced.

#define THRESH 0.6f

__global__ __launch_bounds__(256) void loss_synonymy_kernel(
    const float4* __restrict__ s1,
    const float4* __restrict__ s2,
    const float*  __restrict__ score,
    float*        __restrict__ out,
    int B)
{
    const int tid      = blockIdx.x * blockDim.x + threadIdx.x;
    const int lane     = threadIdx.x & 31;          // lane within half-wave (row group)
    const int halfwave = tid >> 5;                  // global half-wave id
    const int nHalf    = (gridDim.x * blockDim.x) >> 5;

    float acc = 0.0f;

    for (int row = halfwave; row < B; row += nHalf) {
        const size_t base = (size_t)row * 32 + lane;   // 32 float4 per row
        float4 a = s1[base];
        float4 b = s2[base];
        float dx = a.x - b.x;
        float dy = a.y - b.y;
        float dz = a.z - b.z;
        float dw = a.w - b.w;
        float s = dx * dx + dy * dy + dz * dz + dw * dw;

        // Reduce across the 32 lanes of this half-wave (wave=64; xor masks <32
        // stay within the half).
        s += __shfl_xor(s, 16);
        s += __shfl_xor(s, 8);
        s += __shfl_xor(s, 4);
        s += __shfl_xor(s, 2);
        s += __shfl_xor(s, 1);

        if (lane == 0) {
            float dist = sqrtf(s);
            float t = tanhf(dist);
            float sc = score[row];
            // relu kept for exact semantic parity (it is a no-op for t in [0,1))
            float e = (sc >= THRESH) ? fmaxf(1.0f - t, 0.0f)
                                     : fmaxf(1.0f + t, 0.0f);
            acc += e;
        }
    }

    // acc is nonzero only on lanes 0 and 32 of each wave; full xor-reduce is
    // still correct (other lanes contribute 0).
    acc += __shfl_xor(acc, 32);
    acc += __shfl_xor(acc, 16);
    acc += __shfl_xor(acc, 8);
    acc += __shfl_xor(acc, 4);
    acc += __shfl_xor(acc, 2);
    acc += __shfl_xor(acc, 1);

    __shared__ float wsum[4];                       // 256 threads = 4 waves
    const int waveId = threadIdx.x >> 6;
    if ((threadIdx.x & 63) == 0) wsum[waveId] = acc;
    __syncthreads();

    if (threadIdx.x == 0) {
        float blockSum = wsum[0] + wsum[1] + wsum[2] + wsum[3];
        atomicAdd(out, blockSum);                   // device-scope by default
    }
}

extern "C" void kernel_launch(void* const* d_in, const int* in_sizes, int n_in,
                              void* d_out, int out_size, void* d_ws, size_t ws_size,
                              hipStream_t stream) {
    const float4* s1    = (const float4*)d_in[0];
    const float4* s2    = (const float4*)d_in[1];
    const float*  score = (const float*)d_in[2];
    float*        out   = (float*)d_out;

    const int B = in_sizes[2];                      // synonymy_score has B elements

    // d_out is poisoned 0xAA before every timed launch — zero it (async, capturable).
    hipMemsetAsync(d_out, 0, sizeof(float), stream);

    const int block = 256;
    const int grid  = 4096;                         // 16 blocks/CU worth of work, grid-stride
    loss_synonymy_kernel<<<grid, block, 0, stream>>>(s1, s2, score, out, B);
}